// Round 1
// baseline (198.708 us; speedup 1.0000x reference)
//
#include <hip/hip_runtime.h>

#define B_SAMPLES 1024
#define T_LEN     2048
#define MAX_LAG   512
#define TPB       256

// Kernel 1: one block per sample. Stage trajectory in LDS, each thread
// computes full MSD + loss term for 2 lags, block-reduce sum of d^2.
__global__ __launch_bounds__(TPB) void msd_partial_kernel(
    const float* __restrict__ alpha, const float* __restrict__ d0p,
    const float* __restrict__ traj, float* __restrict__ partial) {
  const int b = blockIdx.x;
  __shared__ float2 s[T_LEN];
  __shared__ float wsum[TPB / 64];

  const float2* tr = reinterpret_cast<const float2*>(traj) + (size_t)b * T_LEN;
  for (int i = threadIdx.x; i < T_LEN; i += TPB) s[i] = tr[i];
  __syncthreads();

  const float a  = alpha[b];
  const float d0 = d0p[b];

  float acc = 0.f;
  for (int l = threadIdx.x; l < MAX_LAG; l += TPB) {
    const int lag = l + 1;
    const int n   = T_LEN - lag;           // always >= 1536
    float sum = 0.f;
    #pragma unroll 4
    for (int t = 0; t < n; ++t) {
      float2 p = s[t];                     // broadcast across lanes
      float2 q = s[t + lag];               // stride-1 float2 across lanes (2-way, free)
      float dx = q.x - p.x;
      float dy = q.y - p.y;
      sum = fmaf(dx, dx, fmaf(dy, dy, sum));
    }
    float msd  = sum / (float)n;
    float theo = 4.0f * d0 * expf(a * logf((float)lag));
    float d    = logf(theo + 1e-8f) - logf(msd + 1e-8f);
    acc = fmaf(d, d, acc);
  }

  // wave reduce (64 lanes), then cross-wave via LDS
  for (int off = 32; off > 0; off >>= 1) acc += __shfl_down(acc, off, 64);
  const int wid  = threadIdx.x >> 6;
  const int lane = threadIdx.x & 63;
  if (lane == 0) wsum[wid] = acc;
  __syncthreads();
  if (threadIdx.x == 0) {
    float t2 = 0.f;
    #pragma unroll
    for (int w = 0; w < TPB / 64; ++w) t2 += wsum[w];
    partial[b] = t2;
  }
}

// Kernel 2: deterministic final reduction of B partials -> scalar mean.
__global__ __launch_bounds__(256) void reduce_kernel(
    const float* __restrict__ partial, float* __restrict__ out) {
  __shared__ float wsum[4];
  float acc = 0.f;
  for (int i = threadIdx.x; i < B_SAMPLES; i += 256) acc += partial[i];
  for (int off = 32; off > 0; off >>= 1) acc += __shfl_down(acc, off, 64);
  const int wid  = threadIdx.x >> 6;
  const int lane = threadIdx.x & 63;
  if (lane == 0) wsum[wid] = acc;
  __syncthreads();
  if (threadIdx.x == 0) {
    float t = wsum[0] + wsum[1] + wsum[2] + wsum[3];
    out[0] = t * (1.0f / (float)(B_SAMPLES * MAX_LAG));
  }
}

extern "C" void kernel_launch(void* const* d_in, const int* in_sizes, int n_in,
                              void* d_out, int out_size, void* d_ws, size_t ws_size,
                              hipStream_t stream) {
  const float* alpha = (const float*)d_in[0];   // (B,)
  const float* d0p   = (const float*)d_in[1];   // (B,)
  const float* traj  = (const float*)d_in[2];   // (B, T, 2)
  float* out     = (float*)d_out;               // scalar
  float* partial = (float*)d_ws;                // B floats of scratch

  msd_partial_kernel<<<B_SAMPLES, TPB, 0, stream>>>(alpha, d0p, traj, partial);
  reduce_kernel<<<1, 256, 0, stream>>>(partial, out);
}

// Round 2
// 98.813 us; speedup vs baseline: 2.0109x; 2.0109x over previous
//
#include <hip/hip_runtime.h>

#define B_SAMPLES 1024
#define T_LEN     2048
#define MAX_LAG   512
#define TPB       256

typedef float f32x2 __attribute__((ext_vector_type(2)));

__device__ __forceinline__ int SLOT(int i) { return i + (i >> 4); }

__device__ __forceinline__ f32x2 pkfma(f32x2 a, f32x2 b, f32x2 c) {
  f32x2 d;
  asm("v_pk_fma_f32 %0, %1, %2, %3" : "=v"(d) : "v"(a), "v"(b), "v"(c));
  return d;
}
__device__ __forceinline__ f32x2 pkadd(f32x2 a, f32x2 b) {
  f32x2 d;
  asm("v_pk_add_f32 %0, %1, %2" : "=v"(d) : "v"(a), "v"(b));
  return d;
}

// One block per sample. Thread (g = tid&63, h = tid>>6) owns lags
// [8g+1 .. 8g+8] on t-quarter h, with a 15-element sliding register window
// so each 8x8 (t x lag) tile costs 16 ds_read_b64 instead of 128.
__global__ __launch_bounds__(TPB) void msd_partial_kernel(
    const float* __restrict__ alpha, const float* __restrict__ d0p,
    const float* __restrict__ traj, float* __restrict__ partial) {
  const int b = blockIdx.x;
  __shared__ f32x2 sTraj[2176];          // slot(2047)=2174; padded-index layout
  __shared__ float part[4][MAX_LAG];     // per-quarter per-lag SS partials
  __shared__ float wsum[TPB / 64];

  const f32x2* tr = reinterpret_cast<const f32x2*>(traj) + (size_t)b * T_LEN;
  for (int i = threadIdx.x; i < T_LEN; i += TPB) sTraj[SLOT(i)] = tr[i];
  __syncthreads();

  const int g = threadIdx.x & 63;
  const int h = threadIdx.x >> 6;
  const int lagbase = 8 * g + 1;         // lag_r = lagbase + r

  f32x2 acc[8];
  #pragma unroll
  for (int r = 0; r < 8; ++r) acc[r] = (f32x2)(0.f);

  int t0   = 512 * h;
  // main loop covers t in [t0, tEnd) fully unmasked (all 8 lags valid);
  // for h<3: tEnd = 512(h+1); for h=3: tEnd = 2040-8g (multiple of 8 past 1536)
  const int tEnd = (h < 3) ? (512 * h + 512) : (2040 - 8 * g);

  int base = t0 + lagbase;               // window start index
  f32x2 w[15];
  #pragma unroll
  for (int j = 0; j < 7; ++j) w[j] = sTraj[SLOT(base + j)];

  for (; t0 + 8 <= tEnd; t0 += 8) {
    #pragma unroll
    for (int j = 7; j < 15; ++j) w[j] = sTraj[SLOT(base + j)];
    #pragma unroll
    for (int k = 0; k < 8; ++k) {
      f32x2 p  = sTraj[SLOT(t0 + k)];    // uniform across wave -> broadcast
      f32x2 pn = -p;
      #pragma unroll
      for (int r = 0; r < 8; ++r) {
        f32x2 d = pkadd(w[k + r], pn);
        acc[r]  = pkfma(d, d, acc[r]);
      }
    }
    #pragma unroll
    for (int j = 0; j < 7; ++j) w[j] = w[j + 8];
    base += 8;
  }

  // ragged tail: only h==3 has it; t = tEnd+dlt valid for lag_r when r+dlt<7
  if (h == 3) {
    #pragma unroll
    for (int dlt = 0; dlt < 7; ++dlt) {
      const int t = tEnd + dlt;          // tEnd = 2040-8g >= 1536, t <= 2046
      f32x2 p = sTraj[SLOT(t)];
      #pragma unroll
      for (int r = 0; r < 7; ++r) {
        if (r + dlt < 7) {               // t < T - lag_r
          f32x2 q = sTraj[SLOT(t + lagbase + r)];
          f32x2 d = q - p;
          acc[r] += d * d;
        }
      }
    }
  }

  #pragma unroll
  for (int r = 0; r < 8; ++r) part[h][8 * g + r] = acc[r].x + acc[r].y;
  __syncthreads();

  // per-lag loss terms; each thread handles lags tid+1 and tid+257
  const float a  = alpha[b];
  const float d0 = d0p[b];
  float loc = 0.f;
  #pragma unroll
  for (int c = 0; c < 2; ++c) {
    const int L = threadIdx.x + 256 * c;          // lag-1 index in [0,512)
    float ss = part[0][L] + part[1][L] + part[2][L] + part[3][L];
    const float lag = (float)(L + 1);
    const float n   = (float)(T_LEN - (L + 1));
    float msd  = ss / n;
    float theo = 4.0f * d0 * powf(lag, a);
    float d    = logf(theo + 1e-8f) - logf(msd + 1e-8f);
    loc = fmaf(d, d, loc);
  }

  for (int off = 32; off > 0; off >>= 1) loc += __shfl_down(loc, off, 64);
  const int wid  = threadIdx.x >> 6;
  const int lane = threadIdx.x & 63;
  if (lane == 0) wsum[wid] = loc;
  __syncthreads();
  if (threadIdx.x == 0) {
    partial[b] = wsum[0] + wsum[1] + wsum[2] + wsum[3];
  }
}

__global__ __launch_bounds__(256) void reduce_kernel(
    const float* __restrict__ partial, float* __restrict__ out) {
  __shared__ float wsum[4];
  float acc = 0.f;
  for (int i = threadIdx.x; i < B_SAMPLES; i += 256) acc += partial[i];
  for (int off = 32; off > 0; off >>= 1) acc += __shfl_down(acc, off, 64);
  const int wid  = threadIdx.x >> 6;
  const int lane = threadIdx.x & 63;
  if (lane == 0) wsum[wid] = acc;
  __syncthreads();
  if (threadIdx.x == 0) {
    float t = wsum[0] + wsum[1] + wsum[2] + wsum[3];
    out[0] = t * (1.0f / (float)(B_SAMPLES * MAX_LAG));
  }
}

extern "C" void kernel_launch(void* const* d_in, const int* in_sizes, int n_in,
                              void* d_out, int out_size, void* d_ws, size_t ws_size,
                              hipStream_t stream) {
  const float* alpha = (const float*)d_in[0];
  const float* d0p   = (const float*)d_in[1];
  const float* traj  = (const float*)d_in[2];
  float* out     = (float*)d_out;
  float* partial = (float*)d_ws;

  msd_partial_kernel<<<B_SAMPLES, TPB, 0, stream>>>(alpha, d0p, traj, partial);
  reduce_kernel<<<1, 256, 0, stream>>>(partial, out);
}

// Round 4
// 30.224 us; speedup vs baseline: 6.5745x; 3.2693x over previous
//
#include <hip/hip_runtime.h>

#define B_SAMPLES 1024
#define T_LEN     2048
#define NLAG      512
#define ROWW      172   // uint words per Z row (u capacity); 688 B, stride 172%32=12 -> 2-way banks

typedef _Float16 half8_t __attribute__((ext_vector_type(8)));
typedef float    floatx4 __attribute__((ext_vector_type(4)));

__device__ __forceinline__ int slotP(int k) { return k + (k >> 5); }

// One block (128 thr = 2 waves) per sample b. Z holds transposed packed-f16
// trajectory: word Zw[j*ROWW + u] = {f16(x[16u+j]), f16(y[16u+j])}, zero-padded
// for u >= 128. Wave w computes G_v for v in [16w, 16w+16] via MFMA and emits
// per-lag loss terms for lags [256w+1 .. 256w+255+w] (+ lag 512 on wave 1).
__global__ __launch_bounds__(128) void msd_mfma_kernel(
    const float* __restrict__ alpha, const float* __restrict__ d0p,
    const float* __restrict__ traj, float* __restrict__ partial) {
  const int b   = blockIdx.x;
  const int tid = threadIdx.x;
  const int w   = tid >> 6;
  const int l   = tid & 63;
  const int g   = l >> 4;
  const int p16 = l & 15;

  __shared__ __align__(16) unsigned int Zw[16 * ROWW];  // 11008 B
  __shared__ float Pb[2116];                            // 8464 B (padded prefix)

  // zero pad region u in [128,172)
  for (int k = tid; k < 16 * 44; k += 128) {
    Zw[(k / 44) * ROWW + 128 + (k % 44)] = 0u;
  }

  // stage: wave w covers t in [1024w, 1024w+1024), coalesced float2 loads
  const float2* tr = reinterpret_cast<const float2*>(traj) + (size_t)b * T_LEN;
  for (int s = 0; s < 16; ++s) {
    int t = (w << 10) + (s << 6) + l;
    float2 v2 = tr[t];
    _Float16 hx = (_Float16)v2.x;
    _Float16 hy = (_Float16)v2.y;
    unsigned int word = (unsigned int)__builtin_bit_cast(unsigned short, hx)
                      | ((unsigned int)__builtin_bit_cast(unsigned short, hy) << 16);
    Zw[(t & 15) * ROWW + (t >> 4)] = word;
  }
  __syncthreads();

  // prefix sum of sq[t]=x^2+y^2 (fp32, from f16 data) -> Pb[slotP(k)], k=0..2048.
  // Both waves run it redundantly (identical values -> benign write races).
  const unsigned int* zs = &Zw[2 * l];   // lane's t-chunk [32l,32l+32): u=2l+(i>>4), j=i&15
  float csum = 0.f;
  #pragma unroll
  for (int i = 0; i < 32; ++i) {
    unsigned int word = zs[(i & 15) * ROWW + (i >> 4)];
    float fx = (float)__builtin_bit_cast(_Float16, (unsigned short)(word & 0xffffu));
    float fy = (float)__builtin_bit_cast(_Float16, (unsigned short)(word >> 16));
    csum = fmaf(fx, fx, fmaf(fy, fy, csum));
  }
  float run = csum;
  #pragma unroll
  for (int dlt = 1; dlt < 64; dlt <<= 1) {
    float tsh = __shfl_up(run, dlt, 64);
    if (l >= dlt) run += tsh;
  }
  float excl = run - csum;
  if (l == 0) Pb[0] = 0.f;
  float r2 = excl;
  #pragma unroll
  for (int i = 0; i < 32; ++i) {
    unsigned int word = zs[(i & 15) * ROWW + (i >> 4)];
    float fx = (float)__builtin_bit_cast(_Float16, (unsigned short)(word & 0xffffu));
    float fy = (float)__builtin_bit_cast(_Float16, (unsigned short)(word >> 16));
    r2 = fmaf(fx, fx, fmaf(fy, fy, r2));
    int k = 32 * l + i + 1;
    Pb[slotP(k)] = r2;
  }
  float Ptot = Pb[slotP(2048)];   // same-wave LDS program order guarantees RAW

  // A-fragments (unshifted operand), fixed across v: e = 32q + 8g + i
  const unsigned int* zrow = &Zw[p16 * ROWW];
  half8_t af[8];
  #pragma unroll
  for (int q = 0; q < 8; ++q) {
    uint4 aw = *reinterpret_cast<const uint4*>(zrow + 16 * q + 4 * g);
    af[q] = __builtin_bit_cast(half8_t, aw);
  }

  const float aexp = alpha[b];
  const float c4d0 = 4.f * d0p[b];

  float prevA = 0.f, lacc = 0.f;
  const int rotb = 4 * g + p16;          // j(g,r=0) + p
  const int idx0 = (l & 48) << 2;        // group base, byte index for bpermute

  const int vS = 16 * w, vE = 16 * w + 16;
  for (int v = vS; v <= vE; ++v) {
    floatx4 D1 = {0.f, 0.f, 0.f, 0.f}, D2 = {0.f, 0.f, 0.f, 0.f};
    const unsigned int* bz = zrow + 4 * g + v;   // shifted operand: +v words = +2v f16
    #pragma unroll
    for (int q = 0; q < 8; ++q) {
      uint4 bw;
      bw.x = bz[16 * q + 0];
      bw.y = bz[16 * q + 1];
      bw.z = bz[16 * q + 2];
      bw.w = bz[16 * q + 3];
      half8_t bf = __builtin_bit_cast(half8_t, bw);
      if (q & 1) D2 = __builtin_amdgcn_mfma_f32_16x16x32_f16(af[q], bf, D2, 0, 0, 0);
      else       D1 = __builtin_amdgcn_mfma_f32_16x16x32_f16(af[q], bf, D1, 0, 0, 0);
    }
    // diagonal rotation: lane (g,p) pulls G[4g+r][(4g+r+p)&15] from its group
    float accA = 0.f, accB = 0.f;
    #pragma unroll
    for (int r = 0; r < 4; ++r) {
      float gv = D1[r] + D2[r];
      int src = idx0 | (((rotb + r) & 15) << 2);
      float got = __builtin_bit_cast(float,
          __builtin_amdgcn_ds_bpermute(src, __builtin_bit_cast(int, gv)));
      bool wrap = (rotb + r) >= 16;
      accA += wrap ? 0.f : got;
      accB += wrap ? got : 0.f;
    }
    if (v > vS) {
      float E = prevA + accB;            // C(16(v-1)+p) partial over this group's rows
      E += __shfl_xor(E, 16, 64);
      E += __shfl_xor(E, 32, 64);
      int lag = ((v - 1) << 4) + p16;
      if (l < 16 && lag >= 1) {
        float Pl = Pb[slotP(lag)];
        int mm = 2048 - lag;
        float Pr = Pb[slotP(mm)];
        float S2  = Pr + (Ptot - Pl);
        float msd = fmaxf((S2 - 2.f * E) / (float)mm, 0.f);
        float theo = c4d0 * __builtin_exp2f(aexp * __builtin_log2f((float)lag));
        float dd = 0.69314718f * (__builtin_log2f(theo + 1e-8f) - __builtin_log2f(msd + 1e-8f));
        lacc = fmaf(dd, dd, lacc);
      }
    }
    prevA = accA;
  }

  if (w == 1) {  // lag = 512 = diag_0(G_32)
    float E = prevA;
    E += __shfl_xor(E, 16, 64);
    E += __shfl_xor(E, 32, 64);
    if (l == 0) {
      float Pl = Pb[slotP(512)];
      float Pr = Pb[slotP(1536)];
      float S2  = Pr + (Ptot - Pl);
      float msd = fmaxf((S2 - 2.f * E) * (1.f / 1536.f), 0.f);
      float theo = c4d0 * __builtin_exp2f(aexp * __builtin_log2f(512.f));
      float dd = 0.69314718f * (__builtin_log2f(theo + 1e-8f) - __builtin_log2f(msd + 1e-8f));
      lacc = fmaf(dd, dd, lacc);
    }
  }

  #pragma unroll
  for (int dlt = 1; dlt < 64; dlt <<= 1) lacc += __shfl_xor(lacc, dlt, 64);
  if (l == 0) partial[2 * b + w] = lacc;
}

__global__ __launch_bounds__(256) void reduce_kernel(
    const float* __restrict__ partial, float* __restrict__ out) {
  __shared__ float wsum[4];
  float acc = 0.f;
  for (int i = threadIdx.x; i < 2 * B_SAMPLES; i += 256) acc += partial[i];
  for (int off = 32; off > 0; off >>= 1) acc += __shfl_down(acc, off, 64);
  const int wid  = threadIdx.x >> 6;
  const int lane = threadIdx.x & 63;
  if (lane == 0) wsum[wid] = acc;
  __syncthreads();
  if (threadIdx.x == 0) {
    float t = wsum[0] + wsum[1] + wsum[2] + wsum[3];
    out[0] = t * (1.0f / ((float)B_SAMPLES * (float)NLAG));
  }
}

extern "C" void kernel_launch(void* const* d_in, const int* in_sizes, int n_in,
                              void* d_out, int out_size, void* d_ws, size_t ws_size,
                              hipStream_t stream) {
  const float* alpha = (const float*)d_in[0];
  const float* d0p   = (const float*)d_in[1];
  const float* traj  = (const float*)d_in[2];
  float* out     = (float*)d_out;
  float* partial = (float*)d_ws;   // 2048 floats

  msd_mfma_kernel<<<B_SAMPLES, 128, 0, stream>>>(alpha, d0p, traj, partial);
  reduce_kernel<<<1, 256, 0, stream>>>(partial, out);
}

// Round 5
// 20.513 us; speedup vs baseline: 9.6869x; 1.4734x over previous
//
#include <hip/hip_runtime.h>

#define B_SAMPLES 1024
#define T_LEN     2048
#define NLAG      512
#define ROWW      172   // uint words per Z row; 172%32=12 -> balanced quad spread for b128

typedef _Float16 half8_t __attribute__((ext_vector_type(8)));
typedef float    floatx4 __attribute__((ext_vector_type(4)));

__device__ __forceinline__ int slotP(int k) { return k + (k >> 5); }

// One block (128 thr = 2 waves) per sample. Wave w computes G_v for
// v in [16w, 16w+16] via MFMA with q-outer sliding B-windows.
__global__ __launch_bounds__(128) void msd_mfma_kernel(
    const float* __restrict__ alpha, const float* __restrict__ d0p,
    const float* __restrict__ traj, float* __restrict__ partial) {
  const int b   = blockIdx.x;
  const int tid = threadIdx.x;
  const int w   = tid >> 6;
  const int l   = tid & 63;
  const int g   = l >> 4;
  const int p16 = l & 15;

  __shared__ __align__(16) unsigned int Zw[16 * ROWW];  // 11008 B
  __shared__ float Pb[2116];                            // padded prefix sums

  // zero pad u in [128,172)
  for (int k = tid; k < 16 * 44; k += 128)
    Zw[(k / 44) * ROWW + 128 + (k % 44)] = 0u;

  // stage: wave w covers t in [1024w, 1024w+1024), coalesced float2 loads
  const float2* tr = reinterpret_cast<const float2*>(traj) + (size_t)b * T_LEN;
  #pragma unroll
  for (int s = 0; s < 16; ++s) {
    int t = (w << 10) + (s << 6) + l;
    float2 v2 = tr[t];
    _Float16 hx = (_Float16)v2.x;
    _Float16 hy = (_Float16)v2.y;
    unsigned int word = (unsigned int)__builtin_bit_cast(unsigned short, hx)
                      | ((unsigned int)__builtin_bit_cast(unsigned short, hy) << 16);
    Zw[(t & 15) * ROWW + (t >> 4)] = word;
  }
  __syncthreads();

  // wave 0 only: fp32 prefix sums of |x_t|^2 -> Pb[slotP(0..2048)]
  if (w == 0) {
    const unsigned int* zs = &Zw[2 * l];
    float csum = 0.f;
    #pragma unroll
    for (int i = 0; i < 32; ++i) {
      unsigned int word = zs[(i & 15) * ROWW + (i >> 4)];
      float fx = (float)__builtin_bit_cast(_Float16, (unsigned short)(word & 0xffffu));
      float fy = (float)__builtin_bit_cast(_Float16, (unsigned short)(word >> 16));
      csum = fmaf(fx, fx, fmaf(fy, fy, csum));
    }
    float run = csum;
    #pragma unroll
    for (int dlt = 1; dlt < 64; dlt <<= 1) {
      float tsh = __shfl_up(run, dlt, 64);
      if (l >= dlt) run += tsh;
    }
    float r2 = run - csum;            // exclusive prefix for this lane's chunk
    if (l == 0) Pb[0] = 0.f;
    #pragma unroll
    for (int i = 0; i < 32; ++i) {
      unsigned int word = zs[(i & 15) * ROWW + (i >> 4)];
      float fx = (float)__builtin_bit_cast(_Float16, (unsigned short)(word & 0xffffu));
      float fy = (float)__builtin_bit_cast(_Float16, (unsigned short)(word >> 16));
      r2 = fmaf(fx, fx, fmaf(fy, fy, r2));
      Pb[slotP(32 * l + i + 1)] = r2;
    }
  }

  const unsigned int* zrow = &Zw[p16 * ROWW];
  const int vS = 16 * w;

  floatx4 D[17];
  #pragma unroll
  for (int r = 0; r < 17; ++r) D[r] = (floatx4){0.f, 0.f, 0.f, 0.f};

  #pragma unroll
  for (int q = 0; q < 8; ++q) {
    const unsigned int* wp = zrow + 16 * q + 4 * g + vS;   // 16B-aligned
    uint4 w0 = *reinterpret_cast<const uint4*>(wp);
    uint4 w1 = *reinterpret_cast<const uint4*>(wp + 4);
    uint4 w2 = *reinterpret_cast<const uint4*>(wp + 8);
    uint4 w3 = *reinterpret_cast<const uint4*>(wp + 12);
    uint4 w4 = *reinterpret_cast<const uint4*>(wp + 16);
    unsigned int win[20] = {w0.x, w0.y, w0.z, w0.w,  w1.x, w1.y, w1.z, w1.w,
                            w2.x, w2.y, w2.z, w2.w,  w3.x, w3.y, w3.z, w3.w,
                            w4.x, w4.y, w4.z, w4.w};
    half8_t aq;
    if (w == 0) {
      aq = __builtin_bit_cast(half8_t, w0);   // vS=0: window start IS the A-frag
    } else {
      uint4 aw = *reinterpret_cast<const uint4*>(zrow + 16 * q + 4 * g);
      aq = __builtin_bit_cast(half8_t, aw);
    }
    #pragma unroll
    for (int r = 0; r < 17; ++r) {
      uint4 bw;
      bw.x = win[r]; bw.y = win[r + 1]; bw.z = win[r + 2]; bw.w = win[r + 3];
      half8_t bf = __builtin_bit_cast(half8_t, bw);
      D[r] = __builtin_amdgcn_mfma_f32_16x16x32_f16(aq, bf, D[r], 0, 0, 0);
    }
  }

  __syncthreads();   // Pb (wave 0) visible to wave 1 before epilogue

  const float Ptot = Pb[slotP(2048)];
  const float aexp = alpha[b];
  const float c4d0 = 4.f * d0p[b];

  float prevA = 0.f, lacc = 0.f;
  const int rotb = 4 * g + p16;
  const int idx0 = (l & 48) << 2;

  #pragma unroll
  for (int r = 0; r < 17; ++r) {
    float accA = 0.f, accB = 0.f;
    #pragma unroll
    for (int rr = 0; rr < 4; ++rr) {
      float gv = D[r][rr];
      int src = idx0 | (((rotb + rr) & 15) << 2);
      float got = __builtin_bit_cast(float,
          __builtin_amdgcn_ds_bpermute(src, __builtin_bit_cast(int, gv)));
      bool wrap = (rotb + rr) >= 16;
      accA += wrap ? 0.f : got;
      accB += wrap ? got : 0.f;
    }
    if (r > 0) {
      float E = prevA + accB;
      E += __shfl_xor(E, 16, 64);
      E += __shfl_xor(E, 32, 64);
      int lag = ((vS + r - 1) << 4) + p16;
      if (l < 16 && lag >= 1) {
        float Pl = Pb[slotP(lag)];
        int mm = 2048 - lag;
        float Pr = Pb[slotP(mm)];
        float S2  = Pr + (Ptot - Pl);
        float msd = fmaxf((S2 - 2.f * E) / (float)mm, 0.f);
        float theo = c4d0 * __builtin_exp2f(aexp * __builtin_log2f((float)lag));
        float dd = 0.69314718f * (__builtin_log2f(theo + 1e-8f) - __builtin_log2f(msd + 1e-8f));
        lacc = fmaf(dd, dd, lacc);
      }
    }
    prevA = accA;
  }

  if (w == 1) {  // lag = 512 = diag_0(G_32)
    float E = prevA;
    E += __shfl_xor(E, 16, 64);
    E += __shfl_xor(E, 32, 64);
    if (l == 0) {
      float Pl = Pb[slotP(512)];
      float Pr = Pb[slotP(1536)];
      float S2  = Pr + (Ptot - Pl);
      float msd = fmaxf((S2 - 2.f * E) * (1.f / 1536.f), 0.f);
      float theo = c4d0 * __builtin_exp2f(aexp * __builtin_log2f(512.f));
      float dd = 0.69314718f * (__builtin_log2f(theo + 1e-8f) - __builtin_log2f(msd + 1e-8f));
      lacc = fmaf(dd, dd, lacc);
    }
  }

  #pragma unroll
  for (int dlt = 1; dlt < 64; dlt <<= 1) lacc += __shfl_xor(lacc, dlt, 64);
  if (l == 0) partial[2 * b + w] = lacc;
}

__global__ __launch_bounds__(256) void reduce_kernel(
    const float* __restrict__ partial, float* __restrict__ out) {
  __shared__ float wsum[4];
  float acc = 0.f;
  for (int i = threadIdx.x; i < 2 * B_SAMPLES; i += 256) acc += partial[i];
  for (int off = 32; off > 0; off >>= 1) acc += __shfl_down(acc, off, 64);
  const int wid  = threadIdx.x >> 6;
  const int lane = threadIdx.x & 63;
  if (lane == 0) wsum[wid] = acc;
  __syncthreads();
  if (threadIdx.x == 0) {
    float t = wsum[0] + wsum[1] + wsum[2] + wsum[3];
    out[0] = t * (1.0f / ((float)B_SAMPLES * (float)NLAG));
  }
}

extern "C" void kernel_launch(void* const* d_in, const int* in_sizes, int n_in,
                              void* d_out, int out_size, void* d_ws, size_t ws_size,
                              hipStream_t stream) {
  const float* alpha = (const float*)d_in[0];
  const float* d0p   = (const float*)d_in[1];
  const float* traj  = (const float*)d_in[2];
  float* out     = (float*)d_out;
  float* partial = (float*)d_ws;   // 2048 floats

  msd_mfma_kernel<<<B_SAMPLES, 128, 0, stream>>>(alpha, d0p, traj, partial);
  reduce_kernel<<<1, 256, 0, stream>>>(partial, out);
}